// Round 4
// baseline (373.807 us; speedup 1.0000x reference)
//
#include <hip/hip_runtime.h>
#include <hip/hip_bf16.h>

#define NLAT_IN  480
#define NLON_IN  960
#define NLAT_OUT 721
#define NLON_OUT 1440
#define KSIZE    9
#define NNZ      20
#define CH       32   // C_IN == C_OUT == 32

typedef __bf16 bf16x8 __attribute__((ext_vector_type(8)));
typedef float  f32x4  __attribute__((ext_vector_type(4)));
typedef unsigned u32x4 __attribute__((ext_vector_type(4)));

__device__ __forceinline__ unsigned short f2bf(float f) {
    unsigned u = __float_as_uint(f);
    u += 0x7fffu + ((u >> 16) & 1u);   // round-to-nearest-even
    return (unsigned short)(u >> 16);
}

// ---------------------------------------------------------------------------
// Kernel 1 (fused): blocks [0, NBLK_WEFF) compute weff, blocks
// [NBLK_WEFF, NBLK_WEFF+5768) do the bilinear resample. Independent passes.
// (Unchanged from round 2 — verified.)
// ---------------------------------------------------------------------------
#define W_TILE   180
#define IN_LD4   31            // 31 float4 = 124 input cols staged
#define LDS_PITCH 129
#define NBLK_WEFF 902          // ceil(721*20 / 16)
#define NBLK_RES  (8 * NLAT_OUT)

__global__ __launch_bounds__(256) void pre_kernel(
        const float* __restrict__ x,
        const float* __restrict__ weight,
        const float* __restrict__ psi_vals,
        unsigned short* __restrict__ xr,
        unsigned short* __restrict__ weff) {
    __shared__ float smem[KSIZE * CH * CH];   // 9216 floats = 36,864 B (union)

    const int bid = blockIdx.x;
    const int t   = threadIdx.x;

    if (bid < NBLK_WEFF) {
        // ---- weff[h][nz][oc][c] = sum_k weight[oc][c][k] * psi_vals[k][h][nz]
        float* wl = smem;                    // [k][oc][c]
        for (int i = 0; i < 9; ++i) {
            int lin = i * 256 + t;           // [0, 2304)
            if (lin < KSIZE * CH * CH / 4) {
                f32x4 v = *(const f32x4*)(weight + lin * 4);
                float vv[4] = {v.x, v.y, v.z, v.w};
#pragma unroll
                for (int q = 0; q < 4; ++q) {
                    int l4 = lin * 4 + q;    // = (oc*CH + c)*KSIZE + k
                    int k  = l4 % KSIZE;
                    int occ = l4 / KSIZE;    // oc*CH + c
                    wl[k * (CH * CH) + occ] = vv[q];
                }
            }
        }
        __syncthreads();

        int hnz = bid * 16 + (t >> 4);
        int cp  = t & 15;
        if (hnz >= NLAT_OUT * NNZ) return;

        float p[KSIZE];
#pragma unroll
        for (int k = 0; k < KSIZE; ++k)
            p[k] = psi_vals[(size_t)k * (NLAT_OUT * NNZ) + hnz];

        unsigned* outp = (unsigned*)weff + (size_t)hnz * (CH * CH / 2) + cp;
#pragma unroll 4
        for (int oc = 0; oc < CH; ++oc) {
            float a0 = 0.f, a1 = 0.f;
            const float* wb = wl + oc * CH + cp * 2;
#pragma unroll
            for (int k = 0; k < KSIZE; ++k) {
                a0 += wb[k * (CH * CH)]     * p[k];
                a1 += wb[k * (CH * CH) + 1] * p[k];
            }
            outp[oc * 16] = (unsigned)f2bf(a0) | ((unsigned)f2bf(a1) << 16);
        }
        return;
    }

    // ---- resample: (480,960) -> (721,1440), channel-last bf16 out ----
    float* ld = smem;                        // uses 2*CH*LDS_PITCH = 8256 floats
    int bid2 = bid - NBLK_WEFF;
    int bx = bid2 & 7;
    int h  = bid2 >> 3;
    int wb = bx * W_TILE;
    int base_in = bx * (W_TILE * 2 / 3);     // = bx*120

    float pos_h = (float)h * (479.0f / 720.0f);
    int h0 = (int)floorf(pos_h);
    if (h0 < 0) h0 = 0;
    if (h0 > NLAT_IN - 2) h0 = NLAT_IN - 2;
    float fh = pos_h - (float)h0;

    for (int i = 0; i < 8; ++i) {
        int lin = i * 256 + t;               // [0, 1984)
        if (lin < 2 * CH * IN_LD4) {
            int r   = lin / (CH * IN_LD4);
            int rem = lin - r * (CH * IN_LD4);
            int c   = rem / IN_LD4;
            int j   = rem - c * IN_LD4;
            int src = base_in + 4 * j;
            if (src >= NLON_IN) src -= NLON_IN;      // only last block
            f32x4 v = *(const f32x4*)(x + ((size_t)c * NLAT_IN + h0 + r) * NLON_IN + src);
            float* dst = ld + (r * CH + c) * LDS_PITCH + 4 * j;
            dst[0] = v.x; dst[1] = v.y; dst[2] = v.z; dst[3] = v.w;
        }
    }
    __syncthreads();

    float ifh = 1.0f - fh;
    for (int i = 0; i < 3; ++i) {
        int d = i * 256 + t;                 // [0, 768)
        if (d >= W_TILE * (CH / 8)) break;   // 720 items
        int w_l = d >> 2;
        int cg  = d & 3;                     // channel group of 8
        int w = wb + w_l;
        float pos_w = (float)w * ((float)NLON_IN / (float)NLON_OUT);
        int w0 = (int)floorf(pos_w);
        float fw = pos_w - (float)w0;
        int wl0 = w0 - base_in;              // [0, 120]
        float ifw = 1.0f - fw;

        unsigned rr[4];
#pragma unroll
        for (int j = 0; j < 4; ++j) {
            int c = cg * 8 + j * 2;
            const float* r0 = ld + c * LDS_PITCH + wl0;
            const float* r1 = r0 + CH * LDS_PITCH;
            float v0 = ifh * (ifw * r0[0] + fw * r0[1]) + fh * (ifw * r1[0] + fw * r1[1]);
            const float* q0 = r0 + LDS_PITCH;
            const float* q1 = r1 + LDS_PITCH;
            float v1 = ifh * (ifw * q0[0] + fw * q0[1]) + fh * (ifw * q1[0] + fw * q1[1]);
            rr[j] = (unsigned)f2bf(v0) | ((unsigned)f2bf(v1) << 16);
        }
        u32x4 uv; uv[0] = rr[0]; uv[1] = rr[1]; uv[2] = rr[2]; uv[3] = rr[3];
        *(u32x4*)((unsigned*)xr + ((size_t)h * NLON_OUT + w) * (CH / 2) + cg * 4) = uv;
    }
}

// ---------------------------------------------------------------------------
// Kernel 2: disco conv via MFMA — BARRIER-FREE, LDS-FREE.
// Evidence (rounds 0-3): all LDS-staged variants land 95-141 µs with every
// pipe idle; per-wave unique xr data ~21 KB (L1/L2-fit), xr total 66 MB
// (L3-fit) -> staging is Common-mistake #7. This version loads B-fragments
// DIRECTLY from global: one bf16x8 per lane, 64 lanes = the contiguous 1 KB
// fragment xr[hi][col0..col0+15][0..31] -> perfect coalescing, reuse via
// L1/L2. No __syncthreads, no LDS -> occupancy limited only by VGPR:
// __launch_bounds__(256,5) caps at 102 VGPR -> 20 independent waves/CU.
// Wave task = (h, 48-col strip); block = 4 waves, consecutive strips of the
// same h -> the 4 waves stream the same weff[h] (L1-shared). XCD swizzle is
// exactly bijective (5408 = 8*676); within an XCD, tasks walk h sequentially
// -> xr live window ~460 KB << 4 MB per-XCD L2.
// A-fragments (weff) keep the verified depth-2 prefetch.
// Fragment maps (HW-verified): A[m=lane&15][k=quad*8+j],
// B[k=quad*8+j][n=lane&15], D[row=quad*4+r][col=lane&15].
// ---------------------------------------------------------------------------
#define WSTRIP   30                       // 1440 / 48
#define NTASK    (NLAT_OUT * WSTRIP)      // 21630
#define NBLK_D   ((NTASK + 3) / 4)        // 5408
#define PER_XCD2 (NBLK_D / 8)             // 676 (exact)

__global__ __launch_bounds__(256, 5) void disco_kernel(
        const unsigned short* __restrict__ xr,     // [721][1440][32] bf16
        const unsigned short* __restrict__ weff,   // [721][20][32][32] bf16
        const int* __restrict__ psi_hi,            // [721][20]
        const int* __restrict__ psi_dw,            // [721][20]
        float* __restrict__ out) {                 // [32][721][1440]
    const int bid = blockIdx.x;
    const int bp  = (bid & 7) * PER_XCD2 + (bid >> 3);   // bijective
    const int task = bp * 4 + (int)(threadIdx.x >> 6);
    if (task >= NTASK) return;          // last block: 2 idle waves, no barrier

    const int h     = task / WSTRIP;
    const int strip = task - h * WSTRIP;
    const int wbase = strip * 48;

    const int lane = threadIdx.x & 63;
    const int l15  = lane & 15;
    const int quad = lane >> 4;
    const int c0   = quad * 8;

    const unsigned short* weff_h = weff + (size_t)h * (NNZ * CH * CH);
    const int* hip_ = psi_hi + h * NNZ;
    const int* dwp  = psi_dw + h * NNZ;

    // ---- A prologue: prefetch nz=0,1 weff fragments + psi entries ----
    bf16x8 pa0[2], pa1[2];
    int phi[2], pdw[2];
#pragma unroll
    for (int q = 0; q < 2; ++q) {
        const unsigned short* wp = weff_h + q * (CH * CH);
        pa0[q] = *(const bf16x8*)(wp + l15 * CH + c0);
        pa1[q] = *(const bf16x8*)(wp + (16 + l15) * CH + c0);
        phi[q] = hip_[q];
        pdw[q] = dwp[q];
    }

    f32x4 acc[2][3] = {};
    const int cb0 = wbase + l15;         // this lane's s=0 output column

#pragma unroll
    for (int nz = 0; nz < NNZ; ++nz) {
        const int sl = nz & 1;           // static after full unroll
        bf16x8 a0 = pa0[sl];
        bf16x8 a1 = pa1[sl];
        int hi = phi[sl];
        int dw = pdw[sl];
        if (nz + 2 < NNZ) {              // refill slot 2 nz ahead
            const unsigned short* wp = weff_h + (nz + 2) * (CH * CH);
            pa0[sl] = *(const bf16x8*)(wp + l15 * CH + c0);
            pa1[sl] = *(const bf16x8*)(wp + (16 + l15) * CH + c0);
            phi[sl] = hip_[nz + 2];
            pdw[sl] = dwp[nz + 2];
        }
        int shift = dw > 720 ? dw - NLON_OUT : dw;   // data range: [-10,10]
        int cb = cb0 + shift;                        // [-10, 1432]
        if (cb < 0) cb += NLON_OUT;                  // periodic wrap (low)
        const unsigned short* xrow = xr + (size_t)hi * (NLON_OUT * CH);
#pragma unroll
        for (int s = 0; s < 3; ++s) {
            int cc = cb + s * 16;
            cc = cc >= NLON_OUT ? cc - NLON_OUT : cc;   // periodic wrap (high)
            bf16x8 b = *(const bf16x8*)(xrow + (size_t)cc * CH + c0);
            acc[0][s] = __builtin_amdgcn_mfma_f32_16x16x32_bf16(a0, b, acc[0][s], 0, 0, 0);
            acc[1][s] = __builtin_amdgcn_mfma_f32_16x16x32_bf16(a1, b, acc[1][s], 0, 0, 0);
        }
    }

#pragma unroll
    for (int hh = 0; hh < 2; ++hh)
#pragma unroll
        for (int s = 0; s < 3; ++s)
#pragma unroll
            for (int r = 0; r < 4; ++r) {
                int oc = hh * 16 + quad * 4 + r;
                int w  = wbase + s * 16 + l15;
                out[((size_t)oc * NLAT_OUT + h) * NLON_OUT + w] = acc[hh][s][r];
            }
}

// ---------------------------------------------------------------------------
extern "C" void kernel_launch(void* const* d_in, const int* in_sizes, int n_in,
                              void* d_out, int out_size, void* d_ws, size_t ws_size,
                              hipStream_t stream) {
    const float* x        = (const float*)d_in[0];
    const float* weight   = (const float*)d_in[1];
    const float* psi_vals = (const float*)d_in[2];
    const int*   psi_hi   = (const int*)d_in[3];
    const int*   psi_dw   = (const int*)d_in[4];
    float* out = (float*)d_out;

    // workspace: xr bf16 [721][1440][32] = 66,447,360 B, then
    // weff bf16 [721][20][32][32] = 29,532,160 B
    unsigned short* xr = (unsigned short*)d_ws;
    unsigned short* wf = (unsigned short*)((char*)d_ws + (size_t)NLAT_OUT * NLON_OUT * CH * 2);

    {
        pre_kernel<<<NBLK_WEFF + NBLK_RES, 256, 0, stream>>>(x, weight, psi_vals, xr, wf);
    }
    {
        disco_kernel<<<NBLK_D, 256, 0, stream>>>(xr, wf, psi_hi, psi_dw, out);
    }
}